// Round 1
// baseline (1516.099 us; speedup 1.0000x reference)
//
#include <hip/hip_runtime.h>

#define T_   128
#define B_   256
#define C_   512
#define H_   512
#define L_   26
#define NCLS 6736
#define NPAD 6784   // 53*128, padded N for final GEMM

typedef __attribute__((ext_vector_type(8))) short short8;
typedef __attribute__((ext_vector_type(4))) float f32x4;

__device__ __forceinline__ unsigned short f2b(float f) {
    union { float f; unsigned int u; } v; v.f = f;
    unsigned int r = (v.u + 0x7fffu + ((v.u >> 16) & 1u)) >> 16;
    return (unsigned short)r;
}
__device__ __forceinline__ float b2f(unsigned short u) {
    union { unsigned int u; float f; } v; v.u = ((unsigned int)u) << 16;
    return v.f;
}
__device__ __forceinline__ float tanh_fast(float x) {
    float e = __expf(2.f * x);
    return 1.f - 2.f / (e + 1.f);
}
__device__ __forceinline__ float sigm(float x) {
    return 1.f / (1.f + __expf(-x));
}
__device__ __forceinline__ void llds16(const unsigned short* g, unsigned short* l) {
    __builtin_amdgcn_global_load_lds(
        (const __attribute__((address_space(1))) void*)g,
        (__attribute__((address_space(3))) void*)l, 16, 0, 0);
}

// ---------------- prep: casts + zero-init h ----------------
__global__ __launch_bounds__(256) void prep_kernel(
    const float* __restrict__ feats, const float* __restrict__ W_i2h,
    const float* __restrict__ W_gen, const float* __restrict__ W_h2h,
    const float* __restrict__ W_hh, const float* __restrict__ W_ih,
    unsigned short* __restrict__ feats16, unsigned short* __restrict__ wi2h16,
    unsigned short* __restrict__ wgen16, unsigned short* __restrict__ w2hT16,
    unsigned short* __restrict__ whh16, unsigned short* __restrict__ wih16,
    float* __restrict__ h32, unsigned short* __restrict__ h16)
{
    size_t idx = (size_t)blockIdx.x * 256 + threadIdx.x;   // 16,777,216 total
    feats16[idx] = f2b(feats[idx]);
    if (idx < (size_t)H_ * C_) wi2h16[idx] = f2b(W_i2h[idx]);
    if (idx < (size_t)NPAD * H_)
        wgen16[idx] = (idx < (size_t)NCLS * H_) ? f2b(W_gen[idx]) : (unsigned short)0;
    // W_h2h transposed: w2hT[k*512 + i] = W_h2h[i][k]  (for in-block hp matvec)
    if (idx < (size_t)H_ * H_)
        w2hT16[idx] = f2b(W_h2h[(idx & 511) * 512 + (idx >> 9)]);
    if (idx < (size_t)1536 * 512) {
        whh16[idx] = f2b(W_hh[idx]);
        wih16[idx] = f2b(W_ih[idx]);
    }
    if (idx < (size_t)B_ * H_) { h32[idx] = 0.f; h16[idx] = 0; }
}

// ---------------- bf16 MFMA GEMM, C = A @ B^T (+bias), XCD swizzle ----------------
template<int OUTMODE>   // 0: bf16 out (ld=N)  1: f32 out + bias + col<ncols guard (ld=ncols)
__global__ __launch_bounds__(256) void gemm_bt(
    const unsigned short* __restrict__ A, const unsigned short* __restrict__ B,
    void* __restrict__ outp, const float* __restrict__ bias,
    int M, int N, int K, int ncols)
{
    __shared__ unsigned short As[128 * 32];
    __shared__ unsigned short Bs[128 * 32];
    const int tid = threadIdx.x;
    const int lane = tid & 63;

    const int gridN = (int)gridDim.x, gridM = (int)gridDim.y;
    const int bid = (int)blockIdx.y * gridN + (int)blockIdx.x;
    const int GM = 8;
    const int per = GM * gridN;
    const int grp = bid / per;
    const int rem = bid - grp * per;
    const int gsz0 = gridM - grp * GM;
    const int gsz = gsz0 < GM ? gsz0 : GM;
    const int m0 = (grp * GM + rem % gsz) * 128;
    const int n0 = (rem / gsz) * 128;

    const int wv = tid >> 6;
    const int wm = (wv >> 1) * 64;
    const int wn = (wv & 1) * 64;

    f32x4 acc[4][4];
#pragma unroll
    for (int i = 0; i < 4; i++)
#pragma unroll
        for (int j = 0; j < 4; j++) acc[i][j] = (f32x4)0.f;

    for (int k0 = 0; k0 < K; k0 += 32) {
        __syncthreads();
#pragma unroll
        for (int is = 0; is < 2; ++is) {
            int c = is * 256 + tid;
            int row = c >> 2, col = (c & 3) * 8;
            llds16(A + (size_t)(m0 + row) * K + k0 + col, &As[c * 8]);
            llds16(B + (size_t)(n0 + row) * K + k0 + col, &Bs[c * 8]);
        }
        __syncthreads();
        short8 af[4], bf[4];
#pragma unroll
        for (int t = 0; t < 4; t++) {
            af[t] = *(const short8*)&As[(wm + t * 16 + (lane & 15)) * 32 + (lane >> 4) * 8];
            bf[t] = *(const short8*)&Bs[(wn + t * 16 + (lane & 15)) * 32 + (lane >> 4) * 8];
        }
#pragma unroll
        for (int i = 0; i < 4; i++)
#pragma unroll
            for (int j = 0; j < 4; j++)
                acc[i][j] = __builtin_amdgcn_mfma_f32_16x16x32_bf16(af[i], bf[j], acc[i][j], 0, 0, 0);
    }

    const int cr = (lane >> 4) * 4;
    const int cc = lane & 15;
    if constexpr (OUTMODE == 0) {
        unsigned short* o = (unsigned short*)outp;
#pragma unroll
        for (int i = 0; i < 4; i++)
#pragma unroll
            for (int j = 0; j < 4; j++) {
                int col = n0 + wn + j * 16 + cc;
#pragma unroll
                for (int r = 0; r < 4; r++) {
                    int row = m0 + wm + i * 16 + cr + r;
                    o[(size_t)row * N + col] = f2b(acc[i][j][r]);
                }
            }
    } else {
        float* o = (float*)outp;
#pragma unroll
        for (int j = 0; j < 4; j++) {
            int col = n0 + wn + j * 16 + cc;
            if (col < ncols) {
                float bv = bias[col];
#pragma unroll
                for (int i = 0; i < 4; i++)
#pragma unroll
                    for (int r = 0; r < 4; r++) {
                        int row = m0 + wm + i * 16 + cr + r;
                        o[(size_t)row * ncols + col] = acc[i][j][r] + bv;
                    }
            }
        }
    }
}

// ---------------- fused attention (+ in-block hp): h -> hp -> e -> softmax -> ctx --
// One block per b, 1024 threads (16 waves). hp[b,:] computed in-block from
// transposed W_h2h (L2-resident, lane-coalesced u16 reads), removing gemm_hg.
__global__ __launch_bounds__(1024) void attn_mega(
    const unsigned short* __restrict__ fp, const unsigned short* __restrict__ feats16,
    const unsigned short* __restrict__ h16, const unsigned short* __restrict__ w2hT,
    const float* __restrict__ b_h2h, const float* __restrict__ wscore,
    unsigned short* __restrict__ ctx16)
{
    const int b = blockIdx.x;
    const int tid = threadIdx.x, lane = tid & 63, wv = tid >> 6;
    __shared__ float se[T_];
    __shared__ float ctx4[4][C_];
    __shared__ float shp[H_];
    __shared__ float shh[H_];

    if (tid < H_) shh[tid] = b2f(h16[(size_t)b * H_ + tid]);
    __syncthreads();

    // hp[col] = b_h2h[col] + sum_k h[k] * W_h2h[col][k]; 2-way split over k.
    {
        const int col = tid & (H_ - 1);
        const int kh = tid >> 9;                 // 0 or 1
        const unsigned short* wp = w2hT + (size_t)(kh << 8) * H_ + col;
        const float* hh = &shh[kh << 8];
        float a0 = 0.f, a1 = 0.f;
#pragma unroll 8
        for (int k = 0; k < 256; k += 2) {
            a0 += hh[k]     * b2f(wp[(size_t)k * H_]);
            a1 += hh[k + 1] * b2f(wp[(size_t)(k + 1) * H_]);
        }
        ctx4[kh][col] = a0 + a1;                 // scratch use of ctx4
    }
    __syncthreads();
    if (tid < H_) shp[tid] = ctx4[0][tid] + ctx4[1][tid] + b_h2h[tid];
    __syncthreads();

    float hpr[8], wsr[8];
    {
        const float* wb = wscore + lane * 8;
        const float* hb = &shp[lane * 8];
#pragma unroll
        for (int i = 0; i < 8; i++) { hpr[i] = hb[i]; wsr[i] = wb[i]; }
    }
#pragma unroll
    for (int i = 0; i < 8; i++) {           // 16 waves x 8 t = 128
        int t = wv * 8 + i;
        short8 v = *(const short8*)(fp + ((size_t)t * B_ + b) * H_ + lane * 8);
        float p = 0.f;
#pragma unroll
        for (int j = 0; j < 8; j++)
            p += wsr[j] * tanh_fast(b2f((unsigned short)v[j]) + hpr[j]);
#pragma unroll
        for (int off = 32; off > 0; off >>= 1) p += __shfl_xor(p, off, 64);
        if (lane == 0) se[t] = p;
    }
    __syncthreads();
    if (wv == 0) {
        float v0 = se[lane], v1 = se[lane + 64];
        float mx = fmaxf(v0, v1);
#pragma unroll
        for (int off = 32; off > 0; off >>= 1) mx = fmaxf(mx, __shfl_xor(mx, off, 64));
        float e0 = __expf(v0 - mx), e1 = __expf(v1 - mx);
        float s = e0 + e1;
#pragma unroll
        for (int off = 32; off > 0; off >>= 1) s += __shfl_xor(s, off, 64);
        float inv = 1.f / s;
        se[lane] = e0 * inv; se[lane + 64] = e1 * inv;
    }
    __syncthreads();
    // context: thread handles 2 adjacent c, quarter of the t-range
    const int c = (tid & 255) * 2;
    const int q = tid >> 8;                 // 0..3
    float a0 = 0.f, a1 = 0.f;
    const unsigned short* fb = feats16 + (size_t)b * C_ + c;
    for (int i = 0; i < 32; i++) {
        int t = q * 32 + i;
        float al = se[t];
        unsigned int u = *(const unsigned int*)(fb + (size_t)t * B_ * C_);
        a0 += al * b2f((unsigned short)(u & 0xffffu));
        a1 += al * b2f((unsigned short)(u >> 16));
    }
    ctx4[q][c] = a0; ctx4[q][c + 1] = a1;
    __syncthreads();
    if (tid < C_) {
        float s = ctx4[0][tid] + ctx4[1][tid] + ctx4[2][tid] + ctx4[3][tid];
        ctx16[(size_t)b * C_ + tid] = f2b(s);
    }
}

// ---------------- recurrent GEMM (gi AND gh) + GRU gates fused --------------------
// gi = ctx @ W_ih^T and gh = h @ W_hh^T computed together (6 MFMA chains / tile);
// epilogue applies gates, writes h32/h16/outH. grid (8,16), 256 thr.
__global__ __launch_bounds__(256) void gates_mega(
    const unsigned short* __restrict__ ctx, const unsigned short* __restrict__ wih,
    const unsigned short* __restrict__ hin16, const unsigned short* __restrict__ whh,
    const float* __restrict__ b_ih, const float* __restrict__ b_hh,
    const float* __restrict__ hin32, float* __restrict__ hout32,
    unsigned short* __restrict__ hout16, unsigned short* __restrict__ outH, int step)
{
    const int tid = threadIdx.x, lane = tid & 63, wv = tid >> 6;
    const int m0 = blockIdx.y * 16;
    const int n0 = blockIdx.x * 64 + wv * 16;
    const unsigned short* ap = ctx   + (size_t)(m0 + (lane & 15)) * C_ + (lane >> 4) * 8;
    const unsigned short* ah = hin16 + (size_t)(m0 + (lane & 15)) * H_ + (lane >> 4) * 8;
    const unsigned short* bp = wih + (size_t)(n0 + (lane & 15)) * H_ + (lane >> 4) * 8;
    const unsigned short* bh = whh + (size_t)(n0 + (lane & 15)) * H_ + (lane >> 4) * 8;
    f32x4 ar = (f32x4)0.f, az = (f32x4)0.f, an = (f32x4)0.f;
    f32x4 gr = (f32x4)0.f, gz = (f32x4)0.f, gn = (f32x4)0.f;
#pragma unroll
    for (int k0 = 0; k0 < H_; k0 += 32) {
        short8 a  = *(const short8*)(ap + k0);
        short8 a2 = *(const short8*)(ah + k0);
        short8 br = *(const short8*)(bp + k0);
        short8 bz = *(const short8*)(bp + (size_t)512 * H_ + k0);
        short8 bn = *(const short8*)(bp + (size_t)1024 * H_ + k0);
        short8 cr_ = *(const short8*)(bh + k0);
        short8 cz_ = *(const short8*)(bh + (size_t)512 * H_ + k0);
        short8 cn_ = *(const short8*)(bh + (size_t)1024 * H_ + k0);
        ar = __builtin_amdgcn_mfma_f32_16x16x32_bf16(a,  br,  ar, 0, 0, 0);
        az = __builtin_amdgcn_mfma_f32_16x16x32_bf16(a,  bz,  az, 0, 0, 0);
        an = __builtin_amdgcn_mfma_f32_16x16x32_bf16(a,  bn,  an, 0, 0, 0);
        gr = __builtin_amdgcn_mfma_f32_16x16x32_bf16(a2, cr_, gr, 0, 0, 0);
        gz = __builtin_amdgcn_mfma_f32_16x16x32_bf16(a2, cz_, gz, 0, 0, 0);
        gn = __builtin_amdgcn_mfma_f32_16x16x32_bf16(a2, cn_, gn, 0, 0, 0);
    }
    const int cc = lane & 15, cr = (lane >> 4) * 4;
    const int col = n0 + cc;
    const float bir = b_ih[col], biz = b_ih[512 + col], bin = b_ih[1024 + col];
    const float bhr = b_hh[col], bhz = b_hh[512 + col], bhn = b_hh[1024 + col];
#pragma unroll
    for (int r = 0; r < 4; r++) {
        int row = m0 + cr + r;
        float hv = hin32[(size_t)row * H_ + col];
        float rg = sigm(ar[r] + bir + gr[r] + bhr);
        float zg = sigm(az[r] + biz + gz[r] + bhz);
        float ng = tanh_fast(an[r] + bin + rg * (gn[r] + bhn));
        float hn = (1.f - zg) * ng + zg * hv;
        hout32[(size_t)row * H_ + col] = hn;
        unsigned short hb = f2b(hn);
        hout16[(size_t)row * H_ + col] = hb;
        outH[((size_t)row * L_ + step) * H_ + col] = hb;
    }
}

extern "C" void kernel_launch(void* const* d_in, const int* in_sizes, int n_in,
                              void* d_out, int out_size, void* d_ws, size_t ws_size,
                              hipStream_t stream)
{
    const float* feats   = (const float*)d_in[0];
    const float* W_i2h   = (const float*)d_in[2];
    const float* W_h2h   = (const float*)d_in[3];
    const float* b_h2h   = (const float*)d_in[4];
    const float* W_score = (const float*)d_in[5];
    const float* W_ih    = (const float*)d_in[6];
    const float* W_hh    = (const float*)d_in[7];
    const float* b_ih    = (const float*)d_in[8];
    const float* b_hh    = (const float*)d_in[9];
    const float* W_gen   = (const float*)d_in[10];
    const float* b_gen   = (const float*)d_in[11];

    char* ws = (char*)d_ws;
    size_t off = 0;
    auto alloc = [&](size_t bytes) {
        void* p = ws + off; off += (bytes + 255) & ~(size_t)255; return p;
    };
    unsigned short* feats16 = (unsigned short*)alloc((size_t)T_ * B_ * C_ * 2);
    unsigned short* fp16    = (unsigned short*)alloc((size_t)T_ * B_ * H_ * 2);
    unsigned short* wgen16  = (unsigned short*)alloc((size_t)NPAD * H_ * 2);
    unsigned short* wi2h16  = (unsigned short*)alloc((size_t)H_ * C_ * 2);
    unsigned short* w2hT16  = (unsigned short*)alloc((size_t)H_ * H_ * 2);
    unsigned short* whh16   = (unsigned short*)alloc((size_t)1536 * 512 * 2);
    unsigned short* wih16   = (unsigned short*)alloc((size_t)1536 * 512 * 2);
    unsigned short* outH16  = (unsigned short*)alloc((size_t)B_ * L_ * H_ * 2);
    float* h32a = (float*)alloc((size_t)B_ * H_ * 4);
    float* h32b = (float*)alloc((size_t)B_ * H_ * 4);
    unsigned short* h16a = (unsigned short*)alloc((size_t)B_ * H_ * 2);
    unsigned short* h16b = (unsigned short*)alloc((size_t)B_ * H_ * 2);
    unsigned short* ctx16 = (unsigned short*)alloc((size_t)B_ * C_ * 2);

    prep_kernel<<<dim3((T_ * B_ * C_) / 256), 256, 0, stream>>>(
        feats, W_i2h, W_gen, W_h2h, W_hh, W_ih,
        feats16, wi2h16, wgen16, w2hT16, whh16, wih16, h32a, h16a);

    // feats_proj = feats @ W_i2h^T  -> bf16 [T*B, H]
    gemm_bt<0><<<dim3(H_ / 128, (T_ * B_) / 128), 256, 0, stream>>>(
        feats16, wi2h16, fp16, nullptr, T_ * B_, H_, C_, 0);

    for (int s = 0; s < L_; s++) {
        const float* hin32          = (s & 1) ? h32b : h32a;
        float* hout32               = (s & 1) ? h32a : h32b;
        const unsigned short* hin16 = (s & 1) ? h16b : h16a;
        unsigned short* hout16      = (s & 1) ? h16a : h16b;
        attn_mega<<<dim3(B_), 1024, 0, stream>>>(
            fp16, feats16, hin16, w2hT16, b_h2h, W_score, ctx16);
        gates_mega<<<dim3(8, 16), 256, 0, stream>>>(
            ctx16, wih16, hin16, whh16, b_ih, b_hh, hin32, hout32, hout16, outH16, s);
    }

    // probs = out_h @ W_gen^T + b_gen
    gemm_bt<1><<<dim3(NPAD / 128, (B_ * L_) / 128), 256, 0, stream>>>(
        outH16, wgen16, d_out, b_gen, B_ * L_, NPAD, H_, NCLS);
}